// Round 6
// baseline (131.933 us; speedup 1.0000x reference)
//
#include <hip/hip_runtime.h>
#include <cstddef>

constexpr float GAMMA = 0.99f;
constexpr float GLAM  = 0.99f * 0.95f;   // gamma * gae_lambda
constexpr float ENT_C = 0.01f;

constexpr int T = 65536;
constexpr int O = 8;
constexpr int S = 1048576;               // 2^20
constexpr int BLK = 1024;                // 16 waves/block -> 2 blocks/CU = 32 waves/CU

constexpr int OPPB   = 511;              // opponent blocks; +1 agent block = 512 = 2/CU exactly
constexpr int NQUAD  = O * S / 4;        // 2097152 four-row quads
constexpr int CHUNK  = T / BLK;          // 64 elements per thread in agent scan

typedef float f4 __attribute__((ext_vector_type(4)));
typedef int   i4 __attribute__((ext_vector_type(4)));

// ws layout (floats):
//   ws[0    .. 510 ] : per-block coef-weighted ce partials
//   ws[1024 .. 1534] : per-block coef-weighted smooth-L1 partials
//   ws[2048]         : agent loss

__device__ __forceinline__ float row_ce(float l0, float l1, float l2,
                                        float l3, float l4, float l5, int a)
{
    float m  = fmaxf(fmaxf(fmaxf(l0, l1), fmaxf(l2, l3)), fmaxf(l4, l5));
    float se = __expf(l0 - m) + __expf(l1 - m) + __expf(l2 - m) +
               __expf(l3 - m) + __expf(l4 - m) + __expf(l5 - m);
    float tgt = (a == 0) ? l0 : (a == 1) ? l1 : (a == 2) ? l2 :
                (a == 3) ? l3 : (a == 4) ? l4 : l5;
    return (m + __logf(se)) - tgt;
}

__device__ __forceinline__ float sl1(float v0, float v1, float rw)
{
    float d  = v0 - (rw + GAMMA * v1);
    float ad = fabsf(d);
    return (ad < 1.f) ? 0.5f * d * d : ad - 0.5f;
}

__global__ __launch_bounds__(BLK, 8)
void fused_kernel(const float* __restrict__ arew,
                  const float* __restrict__ alp,
                  const float* __restrict__ aval,
                  const float* __restrict__ aent,
                  const float* __restrict__ olp,
                  const int*   __restrict__ oact,
                  const float* __restrict__ oval,
                  const float* __restrict__ orew,
                  const float* __restrict__ ocoef,
                  float* __restrict__ ws)
{
    const int tid = threadIdx.x;
    __shared__ float s1[BLK], s2[BLK];

    if (blockIdx.x == OPPB) {
        // ----------------- agent loss: blocked reverse linear scan (1024 thr) ------
        const int base = tid * CHUNK;

        float cR = 0.f, cG = 0.f;
        float nextv = aval[base + CHUNK];
        #pragma unroll 4
        for (int k4 = CHUNK - 4; k4 >= 0; k4 -= 4) {
            float4 r4 = *reinterpret_cast<const float4*>(&arew[base + k4]);
            float4 v4 = *reinterpret_cast<const float4*>(&aval[base + k4]);
            cR = GAMMA * cR + r4.w;  cG = GLAM * cG + (r4.w + GAMMA * nextv - v4.w);
            cR = GAMMA * cR + r4.z;  cG = GLAM * cG + (r4.z + GAMMA * v4.w  - v4.z);
            cR = GAMMA * cR + r4.y;  cG = GLAM * cG + (r4.y + GAMMA * v4.z  - v4.y);
            cR = GAMMA * cR + r4.x;  cG = GLAM * cG + (r4.x + GAMMA * v4.y  - v4.x);
            nextv = v4.x;
        }
        s1[tid] = cR; s2[tid] = cG;
        __syncthreads();

        if (tid == 0) {
            double aRd = 1.0, aGd = 1.0;
            for (int i = 0; i < CHUNK; ++i) { aRd *= 0.99; aGd *= 0.99 * 0.95; }
            const float aR = (float)aRd, aG = (float)aGd;
            float Rin = aval[T];
            float Gin = 0.f;
            for (int i = BLK - 1; i >= 0; --i) {
                float cr = s1[i], cg = s2[i];
                s1[i] = Rin; s2[i] = Gin;
                Rin = aR * Rin + cr;
                Gin = aG * Gin + cg;
            }
        }
        __syncthreads();
        float R = s1[tid], g = s2[tid];
        __syncthreads();

        float pl = 0.f, vl = 0.f;
        nextv = aval[base + CHUNK];
        #pragma unroll 4
        for (int k4 = CHUNK - 4; k4 >= 0; k4 -= 4) {
            float4 r4 = *reinterpret_cast<const float4*>(&arew[base + k4]);
            float4 v4 = *reinterpret_cast<const float4*>(&aval[base + k4]);
            float4 l4 = *reinterpret_cast<const float4*>(&alp [base + k4]);
            float4 e4 = *reinterpret_cast<const float4*>(&aent[base + k4]);

            R = GAMMA * R + r4.w; { float adv = R - v4.w; vl += 0.5f * adv * adv; }
            g = GLAM * g + (r4.w + GAMMA * nextv - v4.w); pl += -l4.w * g - ENT_C * e4.w;
            R = GAMMA * R + r4.z; { float adv = R - v4.z; vl += 0.5f * adv * adv; }
            g = GLAM * g + (r4.z + GAMMA * v4.w  - v4.z); pl += -l4.z * g - ENT_C * e4.z;
            R = GAMMA * R + r4.y; { float adv = R - v4.y; vl += 0.5f * adv * adv; }
            g = GLAM * g + (r4.y + GAMMA * v4.z  - v4.y); pl += -l4.y * g - ENT_C * e4.y;
            R = GAMMA * R + r4.x; { float adv = R - v4.x; vl += 0.5f * adv * adv; }
            g = GLAM * g + (r4.x + GAMMA * v4.y  - v4.x); pl += -l4.x * g - ENT_C * e4.x;
            nextv = v4.x;
        }
        s1[tid] = pl; s2[tid] = vl;
        __syncthreads();
        for (int stp = BLK / 2; stp > 0; stp >>= 1) {
            if (tid < stp) { s1[tid] += s1[tid + stp]; s2[tid] += s2[tid + stp]; }
            __syncthreads();
        }
        if (tid == 0) ws[2048] = s1[0] + 0.5f * s2[0];
        return;
    }

    // -------- opponent loss: grid-stride over 4-row quads, 32 waves/CU --------
    const int gtid   = blockIdx.x * BLK + tid;
    const int stride = OPPB * BLK;           // 523264

    float ce_acc = 0.f, sl_acc = 0.f;

    for (int q = gtid; q < NQUAD; q += stride) {
        const int rr   = q << 2;             // flat row index (< 2^23, fits int)
        const int o    = rr >> 20;
        const int srel = rr & (S - 1);
        const float coef = ocoef[o];

        const f4* Lp = reinterpret_cast<const f4*>(olp) + (size_t)q * 6;
        f4 L0 = Lp[0], L1 = Lp[1], L2 = Lp[2], L3 = Lp[3], L4 = Lp[4], L5 = Lp[5];
        i4 ac = *reinterpret_cast<const i4*>(oact + rr);
        f4 v  = *reinterpret_cast<const f4*>(oval + rr);

        const bool lastq = (srel == S - 4);  // quad ends at the final row of this o
        const int  rbi   = rr - o;           // o*(S-1) + srel
        float vext = lastq ? 0.f : oval[rr + 4];
        float w0 = orew[rbi], w1 = orew[rbi + 1], w2 = orew[rbi + 2];
        float w3 = lastq ? 0.f : orew[rbi + 3];

        float ce = row_ce(L0[0], L0[1], L0[2], L0[3], L1[0], L1[1], ac[0])
                 + row_ce(L1[2], L1[3], L2[0], L2[1], L2[2], L2[3], ac[1])
                 + row_ce(L3[0], L3[1], L3[2], L3[3], L4[0], L4[1], ac[2])
                 + row_ce(L4[2], L4[3], L5[0], L5[1], L5[2], L5[3], ac[3]);

        float sl = sl1(v[0], v[1], w0) + sl1(v[1], v[2], w1) + sl1(v[2], v[3], w2);
        if (!lastq) sl += sl1(v[3], vext, w3);

        ce_acc += coef * ce;
        sl_acc += coef * sl;
    }

    s1[tid] = ce_acc; s2[tid] = sl_acc;
    __syncthreads();
    for (int stp = BLK / 2; stp > 0; stp >>= 1) {
        if (tid < stp) { s1[tid] += s1[tid + stp]; s2[tid] += s2[tid + stp]; }
        __syncthreads();
    }
    if (tid == 0) {
        ws[blockIdx.x]        = s1[0];
        ws[1024 + blockIdx.x] = s2[0];
    }
}

__global__ __launch_bounds__(256)
void finalize_kernel(const float* __restrict__ ws, float* __restrict__ out)
{
    const int tid = threadIdx.x;
    __shared__ float r1[256], r2[256];
    float c = 0.f, s = 0.f;
    for (int i = tid; i < OPPB; i += 256) {
        c += ws[i];
        s += ws[1024 + i];
    }
    r1[tid] = c; r2[tid] = s;
    __syncthreads();
    for (int stp = 128; stp > 0; stp >>= 1) {
        if (tid < stp) { r1[tid] += r1[tid + stp]; r2[tid] += r2[tid + stp]; }
        __syncthreads();
    }
    if (tid == 0)
        out[0] = r1[0] / (float)S + r2[0] / (float)(S - 1) + ws[2048];
}

extern "C" void kernel_launch(void* const* d_in, const int* in_sizes, int n_in,
                              void* d_out, int out_size, void* d_ws, size_t ws_size,
                              hipStream_t stream)
{
    const float* arew  = (const float*)d_in[0];
    const float* alp   = (const float*)d_in[1];
    const float* aval  = (const float*)d_in[2];
    const float* aent  = (const float*)d_in[3];
    const float* olp   = (const float*)d_in[4];
    const int*   oact  = (const int*)  d_in[5];
    const float* oval  = (const float*)d_in[6];
    const float* orew  = (const float*)d_in[7];
    const float* ocoef = (const float*)d_in[8];
    float* ws = (float*)d_ws;

    fused_kernel<<<OPPB + 1, BLK, 0, stream>>>(arew, alp, aval, aent,
                                               olp, oact, oval, orew, ocoef, ws);
    finalize_kernel<<<1, 256, 0, stream>>>(ws, (float*)d_out);
}

// Round 7
// 100.215 us; speedup vs baseline: 1.3165x; 1.3165x over previous
//
#include <hip/hip_runtime.h>
#include <cstddef>

constexpr float GAMMA = 0.99f;
constexpr float GLAM  = 0.99f * 0.95f;   // gamma * gae_lambda
constexpr float ENT_C = 0.01f;

constexpr int T = 65536;
constexpr int O = 8;
constexpr int S = 1048576;
constexpr int A = 6;
constexpr int BLK = 256;

constexpr int BPO        = 512;              // opponent blocks per o
constexpr int OPP_BLOCKS = O * BPO;          // 4096
constexpr int ROWS_PER_B = S / BPO;          // 2048 rows per block
constexpr int STAGE_ROWS = 512;              // rows staged per LDS pass
constexpr int NSTAGE     = ROWS_PER_B / STAGE_ROWS;   // 4
constexpr int CHUNK      = T / BLK;          // 256 elements per thread in agent scan

// ws layout (floats):
//   ws[0      .. 4095] : per-block ce partials
//   ws[4096   .. 8191] : per-block smooth-L1 partials
//   ws[8192]           : agent loss

__device__ __forceinline__ float row_ce(float l0, float l1, float l2,
                                        float l3, float l4, float l5, int a)
{
    float m  = fmaxf(fmaxf(fmaxf(l0, l1), fmaxf(l2, l3)), fmaxf(l4, l5));
    float se = __expf(l0 - m) + __expf(l1 - m) + __expf(l2 - m) +
               __expf(l3 - m) + __expf(l4 - m) + __expf(l5 - m);
    float tgt = (a == 0) ? l0 : (a == 1) ? l1 : (a == 2) ? l2 :
                (a == 3) ? l3 : (a == 4) ? l4 : l5;
    return (m + __logf(se)) - tgt;
}

__device__ __forceinline__ float sl1f(float v0, float v1, float rw)
{
    float d  = v0 - (rw + GAMMA * v1);
    float ad = fabsf(d);
    return (ad < 1.f) ? 0.5f * d * d : ad - 0.5f;
}

__global__ __launch_bounds__(BLK)
void fused_kernel(const float* __restrict__ arew,
                  const float* __restrict__ alp,
                  const float* __restrict__ aval,
                  const float* __restrict__ aent,
                  const float* __restrict__ olp,
                  const int*   __restrict__ oact,
                  const float* __restrict__ oval,
                  const float* __restrict__ orew,
                  float* __restrict__ ws)
{
    const int tid = threadIdx.x;
    __shared__ float s1[BLK], s2[BLK];

    if (blockIdx.x == 0) {
        // ----------------- agent loss: blocked reverse linear scan -----------------
        const int base = tid * CHUNK;

        float cR = 0.f, cG = 0.f;
        float nextv = aval[base + CHUNK];
        #pragma unroll 4
        for (int k4 = CHUNK - 4; k4 >= 0; k4 -= 4) {
            float4 r4 = *reinterpret_cast<const float4*>(&arew[base + k4]);
            float4 v4 = *reinterpret_cast<const float4*>(&aval[base + k4]);
            cR = GAMMA * cR + r4.w;  cG = GLAM * cG + (r4.w + GAMMA * nextv - v4.w);
            cR = GAMMA * cR + r4.z;  cG = GLAM * cG + (r4.z + GAMMA * v4.w  - v4.z);
            cR = GAMMA * cR + r4.y;  cG = GLAM * cG + (r4.y + GAMMA * v4.z  - v4.y);
            cR = GAMMA * cR + r4.x;  cG = GLAM * cG + (r4.x + GAMMA * v4.y  - v4.x);
            nextv = v4.x;
        }
        s1[tid] = cR; s2[tid] = cG;
        __syncthreads();

        if (tid == 0) {
            double aRd = 1.0, aGd = 1.0;
            for (int i = 0; i < CHUNK; ++i) { aRd *= 0.99; aGd *= 0.99 * 0.95; }
            const float aR = (float)aRd, aG = (float)aGd;
            float Rin = aval[T];
            float Gin = 0.f;
            for (int i = BLK - 1; i >= 0; --i) {
                float cr = s1[i], cg = s2[i];
                s1[i] = Rin; s2[i] = Gin;
                Rin = aR * Rin + cr;
                Gin = aG * Gin + cg;
            }
        }
        __syncthreads();
        float R = s1[tid], g = s2[tid];
        __syncthreads();

        float pl = 0.f, vl = 0.f;
        nextv = aval[base + CHUNK];
        #pragma unroll 4
        for (int k4 = CHUNK - 4; k4 >= 0; k4 -= 4) {
            float4 r4 = *reinterpret_cast<const float4*>(&arew[base + k4]);
            float4 v4 = *reinterpret_cast<const float4*>(&aval[base + k4]);
            float4 l4 = *reinterpret_cast<const float4*>(&alp [base + k4]);
            float4 e4 = *reinterpret_cast<const float4*>(&aent[base + k4]);

            R = GAMMA * R + r4.w; { float adv = R - v4.w; vl += 0.5f * adv * adv; }
            g = GLAM * g + (r4.w + GAMMA * nextv - v4.w); pl += -l4.w * g - ENT_C * e4.w;
            R = GAMMA * R + r4.z; { float adv = R - v4.z; vl += 0.5f * adv * adv; }
            g = GLAM * g + (r4.z + GAMMA * v4.w  - v4.z); pl += -l4.z * g - ENT_C * e4.z;
            R = GAMMA * R + r4.y; { float adv = R - v4.y; vl += 0.5f * adv * adv; }
            g = GLAM * g + (r4.y + GAMMA * v4.z  - v4.y); pl += -l4.y * g - ENT_C * e4.y;
            R = GAMMA * R + r4.x; { float adv = R - v4.x; vl += 0.5f * adv * adv; }
            g = GLAM * g + (r4.x + GAMMA * v4.y  - v4.x); pl += -l4.x * g - ENT_C * e4.x;
            nextv = v4.x;
        }
        s1[tid] = pl; s2[tid] = vl;
        __syncthreads();
        for (int stp = BLK / 2; stp > 0; stp >>= 1) {
            if (tid < stp) { s1[tid] += s1[tid + stp]; s2[tid] += s2[tid + stp]; }
            __syncthreads();
        }
        if (tid == 0) ws[2 * OPP_BLOCKS] = s1[0] + 0.5f * s2[0];
        return;
    }

    // ------ opponent loss: double-buffered LDS staging, one barrier per stage ------
    __shared__ float lds[2][STAGE_ROWS * A];    // 2 x 12288 B

    const int bid  = blockIdx.x - 1;
    const int o    = bid / BPO;
    const int seg  = bid % BPO;
    const int row0 = seg * ROWS_PER_B;
    const size_t obase = (size_t)o * S;
    const size_t rbase = (size_t)o * (S - 1);

    // prefetch registers (issue early, write late)
    float4 pa, pb, pc; int2 pact; float2 pv; float pv2, pr0, pr1;

    auto issue = [&](int s) {
        const int srow = row0 + s * STAGE_ROWS;
        const float4* lp4 = reinterpret_cast<const float4*>(olp + (obase + srow) * (size_t)A);
        pa = lp4[tid];
        pb = lp4[tid + BLK];
        pc = lp4[tid + 2 * BLK];
        const int r = srow + 2 * tid;                 // this thread's first row
        const size_t gr = obase + r;
        pact = *reinterpret_cast<const int2*>(&oact[gr]);
        pv   = *reinterpret_cast<const float2*>(&oval[gr]);
        pv2  = (r + 2 <= S - 1) ? oval[gr + 2] : 0.f;
        pr0  = orew[rbase + r];                       // r <= S-2 always
        pr1  = (r + 1 < S - 1) ? orew[rbase + r + 1] : 0.f;
    };

    float ce_acc = 0.f, sl_acc = 0.f;
    issue(0);

    #pragma unroll
    for (int s = 0; s < NSTAGE; ++s) {
        float* buf = lds[s & 1];
        // save this stage's side data before regs are recycled
        const int2  act = pact;
        const float2 v  = pv;
        const float v2 = pv2, rw0 = pr0, rw1 = pr1;
        // write this stage's logits to its buffer
        reinterpret_cast<float4*>(buf)[tid]           = pa;
        reinterpret_cast<float4*>(buf)[tid + BLK]     = pb;
        reinterpret_cast<float4*>(buf)[tid + 2 * BLK] = pc;
        // issue next stage's loads into the regs (targets the other buffer next iter)
        if (s + 1 < NSTAGE) issue(s + 1);
        __syncthreads();    // buf visible; also fences prior-iteration reads (WAR across dbuf)

        const int r = row0 + s * STAGE_ROWS + 2 * tid;
        const float* lrow = &buf[12 * tid];
        float4 q0 = *reinterpret_cast<const float4*>(lrow);
        float4 q1 = *reinterpret_cast<const float4*>(lrow + 4);
        float4 q2 = *reinterpret_cast<const float4*>(lrow + 8);

        ce_acc += row_ce(q0.x, q0.y, q0.z, q0.w, q1.x, q1.y, act.x);
        ce_acc += row_ce(q1.z, q1.w, q2.x, q2.y, q2.z, q2.w, act.y);

        {   // smooth-L1, row r (always r < S-1)
            sl_acc += sl1f(v.x, v.y, rw0);
        }
        if (r + 1 < S - 1) {
            sl_acc += sl1f(v.y, v2, rw1);
        }
    }

    s1[tid] = ce_acc; s2[tid] = sl_acc;
    __syncthreads();
    for (int stp = BLK / 2; stp > 0; stp >>= 1) {
        if (tid < stp) { s1[tid] += s1[tid + stp]; s2[tid] += s2[tid + stp]; }
        __syncthreads();
    }
    if (tid == 0) {
        ws[bid]              = s1[0];
        ws[OPP_BLOCKS + bid] = s2[0];
    }
}

__global__ __launch_bounds__(BLK)
void finalize_kernel(const float* __restrict__ ws,
                     const float* __restrict__ coefs,
                     float* __restrict__ out)
{
    const int tid = threadIdx.x;
    __shared__ float r1[BLK], r2[BLK];
    float tot = 0.f;
    for (int o = 0; o < O; ++o) {
        const float* cw = ws + o * BPO;
        const float* sw = ws + OPP_BLOCKS + o * BPO;
        r1[tid] = cw[tid] + cw[tid + BLK];
        r2[tid] = sw[tid] + sw[tid + BLK];
        __syncthreads();
        for (int stp = BLK / 2; stp > 0; stp >>= 1) {
            if (tid < stp) { r1[tid] += r1[tid + stp]; r2[tid] += r2[tid + stp]; }
            __syncthreads();
        }
        if (tid == 0)
            tot += coefs[o] * (r1[0] / (float)S + r2[0] / (float)(S - 1));
        __syncthreads();
    }
    if (tid == 0) out[0] = tot + ws[2 * OPP_BLOCKS];
}

extern "C" void kernel_launch(void* const* d_in, const int* in_sizes, int n_in,
                              void* d_out, int out_size, void* d_ws, size_t ws_size,
                              hipStream_t stream)
{
    const float* arew  = (const float*)d_in[0];
    const float* alp   = (const float*)d_in[1];
    const float* aval  = (const float*)d_in[2];
    const float* aent  = (const float*)d_in[3];
    const float* olp   = (const float*)d_in[4];
    const int*   oact  = (const int*)  d_in[5];
    const float* oval  = (const float*)d_in[6];
    const float* orew  = (const float*)d_in[7];
    const float* ocoef = (const float*)d_in[8];
    float* ws = (float*)d_ws;

    fused_kernel<<<1 + OPP_BLOCKS, BLK, 0, stream>>>(arew, alp, aval, aent,
                                                     olp, oact, oval, orew, ws);
    finalize_kernel<<<1, BLK, 0, stream>>>(ws, ocoef, (float*)d_out);
}